// Round 11
// baseline (387.436 us; speedup 1.0000x reference)
//
#include <hip/hip_runtime.h>

static constexpr int NUSERS = 100000;
static constexpr int NITEMS = 50000;
static constexpr int NNODES = NUSERS + NITEMS;   // 150000
static constexpr int D      = 64;
static constexpr int NNZE   = 4800000;           // COO entries
static constexpr int NVEC4  = NNODES * D / 4;    // 2.4M 4-col groups
static constexpr int NU4    = NUSERS * D / 4;

static constexpr int NB       = 512;                       // buckets
static constexpr int RPB      = (NNODES + NB - 1) / NB;    // 293 rows/bucket
static constexpr int CHUNK    = 4096;                      // edges per part1 block
static constexpr int P1_BLOCKS = (NNZE + CHUNK - 1) / CHUNK; // 1172

__device__ __forceinline__ unsigned bf16rne(float f) {
    unsigned u = __float_as_uint(f);
    return (u + 0x7FFFu + ((u >> 16) & 1u)) >> 16;   // round-to-nearest-even bf16
}
__device__ __forceinline__ float bflo(unsigned u) { return __uint_as_float(u << 16); }
__device__ __forceinline__ float bfhi(unsigned u) { return __uint_as_float(u & 0xFFFF0000u); }

// ---------- stage: x = ego (packed bf16) ----------
__global__ void lg_init(const float4* __restrict__ ue, const float4* __restrict__ ie,
                        uint2* __restrict__ x) {
    int stride = gridDim.x * blockDim.x;
    for (int i = blockIdx.x * blockDim.x + threadIdx.x; i < NVEC4; i += stride) {
        float4 v = (i < NU4) ? ue[i] : ie[i - NU4];
        x[i] = make_uint2(bf16rne(v.x) | (bf16rne(v.y) << 16),
                          bf16rne(v.z) | (bf16rne(v.w) << 16));
    }
}

// ---------- bucket-level histogram: LDS-privatized, int4 loads ----------
__global__ void __launch_bounds__(512)
lg_bcnt(const int* __restrict__ rows, int* __restrict__ bucketCnt) {
    __shared__ int cnt[NB];
    int t = threadIdx.x;
    cnt[t] = 0;
    __syncthreads();
    int c0 = blockIdx.x * CHUNK;
    int c1 = min(c0 + CHUNK, NNZE);
    #pragma unroll
    for (int pass = 0; pass < 2; ++pass) {
        int e = c0 + (pass * 512 + t) * 4;
        if (e < c1) {
            int4 r4 = *(const int4*)(rows + e);
            atomicAdd(&cnt[r4.x / RPB], 1);
            atomicAdd(&cnt[r4.y / RPB], 1);
            atomicAdd(&cnt[r4.z / RPB], 1);
            atomicAdd(&cnt[r4.w / RPB], 1);
        }
    }
    __syncthreads();
    int n = cnt[t];
    if (n) atomicAdd(&bucketCnt[t], n);
}

// ---------- scan 512 bucket counts -> bbase[513]; seed gcur ----------
__global__ void __launch_bounds__(512)
lg_bscan(const int* __restrict__ bucketCnt, int* __restrict__ bbase,
         int* __restrict__ gcur) {
    __shared__ int s[NB];
    int t = threadIdx.x;
    int v = bucketCnt[t];
    s[t] = v;
    __syncthreads();
    for (int off = 1; off < NB; off <<= 1) {
        int tmp = (t >= off) ? s[t - off] : 0;
        __syncthreads();
        s[t] += tmp;
        __syncthreads();
    }
    int ex = s[t] - v;          // exclusive prefix
    bbase[t] = ex;
    gcur[t] = ex;
    if (t == NB - 1) bbase[NB] = s[t];
}

// ---------- phase 1: bucket partition with LDS-sorted staging ----------
// stagec: col | (rowLow << 18); stagev: bf16 edge value
__global__ void __launch_bounds__(512)
lg_part1(const int* __restrict__ rows, const int* __restrict__ cols,
         const float* __restrict__ vals, int* __restrict__ gcur,
         int* __restrict__ stagec, unsigned short* __restrict__ stagev) {
    __shared__ int s_cnt[NB];
    __shared__ int s_lcur[NB];
    __shared__ int s_gofs[NB];
    __shared__ int s_payc[CHUNK];
    __shared__ unsigned short s_payv[CHUNK];
    __shared__ unsigned short s_bid[CHUNK];
    int t = threadIdx.x;
    int c0 = blockIdx.x * CHUNK;
    int c1 = min(c0 + CHUNK, NNZE);
    s_cnt[t] = 0;
    __syncthreads();

    int  eb[8], ep[8]; unsigned short ev[8];
    bool has0, has1;
    {
        int e = c0 + t * 4;
        has0 = e < c1;
        if (has0) {
            int4 r4 = *(const int4*)(rows + e);
            int4 c4 = *(const int4*)(cols + e);
            float4 v4 = *(const float4*)(vals + e);
            eb[0] = r4.x / RPB; ep[0] = c4.x | ((r4.x - eb[0] * RPB) << 18); ev[0] = (unsigned short)bf16rne(v4.x);
            eb[1] = r4.y / RPB; ep[1] = c4.y | ((r4.y - eb[1] * RPB) << 18); ev[1] = (unsigned short)bf16rne(v4.y);
            eb[2] = r4.z / RPB; ep[2] = c4.z | ((r4.z - eb[2] * RPB) << 18); ev[2] = (unsigned short)bf16rne(v4.z);
            eb[3] = r4.w / RPB; ep[3] = c4.w | ((r4.w - eb[3] * RPB) << 18); ev[3] = (unsigned short)bf16rne(v4.w);
            atomicAdd(&s_cnt[eb[0]], 1); atomicAdd(&s_cnt[eb[1]], 1);
            atomicAdd(&s_cnt[eb[2]], 1); atomicAdd(&s_cnt[eb[3]], 1);
        }
        e = c0 + (512 + t) * 4;
        has1 = e < c1;
        if (has1) {
            int4 r4 = *(const int4*)(rows + e);
            int4 c4 = *(const int4*)(cols + e);
            float4 v4 = *(const float4*)(vals + e);
            eb[4] = r4.x / RPB; ep[4] = c4.x | ((r4.x - eb[4] * RPB) << 18); ev[4] = (unsigned short)bf16rne(v4.x);
            eb[5] = r4.y / RPB; ep[5] = c4.y | ((r4.y - eb[5] * RPB) << 18); ev[5] = (unsigned short)bf16rne(v4.y);
            eb[6] = r4.z / RPB; ep[6] = c4.z | ((r4.z - eb[6] * RPB) << 18); ev[6] = (unsigned short)bf16rne(v4.z);
            eb[7] = r4.w / RPB; ep[7] = c4.w | ((r4.w - eb[7] * RPB) << 18); ev[7] = (unsigned short)bf16rne(v4.w);
            atomicAdd(&s_cnt[eb[4]], 1); atomicAdd(&s_cnt[eb[5]], 1);
            atomicAdd(&s_cnt[eb[6]], 1); atomicAdd(&s_cnt[eb[7]], 1);
        }
    }
    __syncthreads();

    int myCnt = s_cnt[t];
    for (int off = 1; off < NB; off <<= 1) {
        int tmp = (t >= off) ? s_cnt[t - off] : 0;
        __syncthreads();
        s_cnt[t] += tmp;
        __syncthreads();
    }
    int lstart = s_cnt[t] - myCnt;
    int gbase = myCnt ? atomicAdd(&gcur[t], myCnt) : 0;
    s_lcur[t] = lstart;
    s_gofs[t] = gbase - lstart;
    __syncthreads();

    #pragma unroll
    for (int k = 0; k < 4; ++k) {
        if (has0) {
            int pos = atomicAdd(&s_lcur[eb[k]], 1);
            s_payc[pos] = ep[k];
            s_payv[pos] = ev[k];
            s_bid[pos] = (unsigned short)eb[k];
        }
    }
    #pragma unroll
    for (int k = 4; k < 8; ++k) {
        if (has1) {
            int pos = atomicAdd(&s_lcur[eb[k]], 1);
            s_payc[pos] = ep[k];
            s_payv[pos] = ev[k];
            s_bid[pos] = (unsigned short)eb[k];
        }
    }
    __syncthreads();

    int n = c1 - c0;
    for (int p = t; p < n; p += 512) {
        int b = s_bid[p];
        int dst = s_gofs[b] + p;
        stagec[dst] = s_payc[p];
        stagev[dst] = s_payv[p];
    }
}

// ---------- phase 2: per-bucket rowptr build + exact CSR placement ----------
__global__ void __launch_bounds__(512)
lg_part2(const int* __restrict__ bbase, const int* __restrict__ stagec,
         const unsigned short* __restrict__ stagev,
         int* __restrict__ csrc, unsigned short* __restrict__ csrv,
         int* __restrict__ rowptr) {
    __shared__ int s[NB];
    __shared__ int lcur[RPB];
    int b = blockIdx.x;
    int t = threadIdx.x;
    int r0 = b * RPB;
    int nrows = min(RPB, NNODES - r0);
    int s0 = bbase[b], s1 = bbase[b + 1];

    s[t] = 0;
    __syncthreads();
    for (int p = s0 + t; p < s1; p += 512)
        atomicAdd(&s[(stagec[p] >> 18) & 511], 1);
    __syncthreads();
    int v = s[t];
    for (int off = 1; off < NB; off <<= 1) {
        int tmp = (t >= off) ? s[t - off] : 0;
        __syncthreads();
        s[t] += tmp;
        __syncthreads();
    }
    int pos0 = s0 + s[t] - v;
    if (t < nrows) {
        rowptr[r0 + t] = pos0;
        lcur[t] = pos0;
    }
    if (b == gridDim.x - 1 && t == 0) rowptr[NNODES] = NNZE;
    __syncthreads();
    for (int p = s0 + t; p < s1; p += 512) {
        int pc = stagec[p];
        unsigned short pv = stagev[p];
        int rl = (pc >> 18) & 511;
        int pos = atomicAdd(&lcur[rl], 1);
        csrc[pos] = pc & 0x3FFFF;
        csrv[pos] = pv;
    }
}

// ---------- pull SpMM: 1 row per 16-lane group, unroll-8, split col/val ----------
__global__ void __launch_bounds__(256)
lg_spmm(const int* __restrict__ rowptr, const int* __restrict__ csrc,
        const unsigned short* __restrict__ csrv,
        const uint2* __restrict__ x, uint2* __restrict__ y) {
    int lane16 = threadIdx.x & 15;
    int r = (blockIdx.x * blockDim.x + threadIdx.x) >> 4;
    if (r >= NNODES) return;
    int p0 = rowptr[r], p1 = rowptr[r + 1];
    float4 acc = {0.f, 0.f, 0.f, 0.f};
    int p = p0;
    for (; p + 8 <= p1; p += 8) {
        int c0 = csrc[p],     c1 = csrc[p + 1], c2 = csrc[p + 2], c3 = csrc[p + 3];
        int c4 = csrc[p + 4], c5 = csrc[p + 5], c6 = csrc[p + 6], c7 = csrc[p + 7];
        unsigned short w0 = csrv[p],     w1 = csrv[p + 1], w2 = csrv[p + 2], w3 = csrv[p + 3];
        unsigned short w4 = csrv[p + 4], w5 = csrv[p + 5], w6 = csrv[p + 6], w7 = csrv[p + 7];
        uint2 x0 = x[c0 * 16 + lane16];
        uint2 x1 = x[c1 * 16 + lane16];
        uint2 x2 = x[c2 * 16 + lane16];
        uint2 x3 = x[c3 * 16 + lane16];
        uint2 x4 = x[c4 * 16 + lane16];
        uint2 x5 = x[c5 * 16 + lane16];
        uint2 x6 = x[c6 * 16 + lane16];
        uint2 x7 = x[c7 * 16 + lane16];
        float v0 = bflo(w0), v1 = bflo(w1), v2 = bflo(w2), v3 = bflo(w3);
        float v4 = bflo(w4), v5 = bflo(w5), v6 = bflo(w6), v7 = bflo(w7);
        acc.x += v0 * bflo(x0.x) + v1 * bflo(x1.x) + v2 * bflo(x2.x) + v3 * bflo(x3.x)
               + v4 * bflo(x4.x) + v5 * bflo(x5.x) + v6 * bflo(x6.x) + v7 * bflo(x7.x);
        acc.y += v0 * bfhi(x0.x) + v1 * bfhi(x1.x) + v2 * bfhi(x2.x) + v3 * bfhi(x3.x)
               + v4 * bfhi(x4.x) + v5 * bfhi(x5.x) + v6 * bfhi(x6.x) + v7 * bfhi(x7.x);
        acc.z += v0 * bflo(x0.y) + v1 * bflo(x1.y) + v2 * bflo(x2.y) + v3 * bflo(x3.y)
               + v4 * bflo(x4.y) + v5 * bflo(x5.y) + v6 * bflo(x6.y) + v7 * bflo(x7.y);
        acc.w += v0 * bfhi(x0.y) + v1 * bfhi(x1.y) + v2 * bfhi(x2.y) + v3 * bfhi(x3.y)
               + v4 * bfhi(x4.y) + v5 * bfhi(x5.y) + v6 * bfhi(x6.y) + v7 * bfhi(x7.y);
    }
    for (; p + 4 <= p1; p += 4) {
        int c0 = csrc[p], c1 = csrc[p + 1], c2 = csrc[p + 2], c3 = csrc[p + 3];
        unsigned short w0 = csrv[p], w1 = csrv[p + 1], w2 = csrv[p + 2], w3 = csrv[p + 3];
        uint2 x0 = x[c0 * 16 + lane16];
        uint2 x1 = x[c1 * 16 + lane16];
        uint2 x2 = x[c2 * 16 + lane16];
        uint2 x3 = x[c3 * 16 + lane16];
        float v0 = bflo(w0), v1 = bflo(w1), v2 = bflo(w2), v3 = bflo(w3);
        acc.x += v0 * bflo(x0.x) + v1 * bflo(x1.x) + v2 * bflo(x2.x) + v3 * bflo(x3.x);
        acc.y += v0 * bfhi(x0.x) + v1 * bfhi(x1.x) + v2 * bfhi(x2.x) + v3 * bfhi(x3.x);
        acc.z += v0 * bflo(x0.y) + v1 * bflo(x1.y) + v2 * bflo(x2.y) + v3 * bflo(x3.y);
        acc.w += v0 * bfhi(x0.y) + v1 * bfhi(x1.y) + v2 * bfhi(x2.y) + v3 * bfhi(x3.y);
    }
    for (; p < p1; ++p) {
        int c = csrc[p];
        float v = bflo(csrv[p]);
        uint2 xv = x[c * 16 + lane16];
        acc.x += v * bflo(xv.x); acc.y += v * bfhi(xv.x);
        acc.z += v * bflo(xv.y); acc.w += v * bfhi(xv.y);
    }
    y[r * 16 + lane16] = make_uint2(bf16rne(acc.x) | (bf16rne(acc.y) << 16),
                                    bf16rne(acc.z) | (bf16rne(acc.w) << 16));
}

// ---------- final combine: out = 0.25 * (ego_fp32 + y1 + y2 + y3) ----------
__global__ void lg_combine(const float4* __restrict__ ue, const float4* __restrict__ ie,
                           const uint2* __restrict__ y1, const uint2* __restrict__ y2,
                           const uint2* __restrict__ y3, float4* __restrict__ out) {
    int stride = gridDim.x * blockDim.x;
    for (int i = blockIdx.x * blockDim.x + threadIdx.x; i < NVEC4; i += stride) {
        float4 e = (i < NU4) ? ue[i] : ie[i - NU4];
        uint2 a = y1[i], b = y2[i], c = y3[i];
        float4 o;
        o.x = (e.x + bflo(a.x) + bflo(b.x) + bflo(c.x)) * 0.25f;
        o.y = (e.y + bfhi(a.x) + bfhi(b.x) + bfhi(c.x)) * 0.25f;
        o.z = (e.z + bflo(a.y) + bflo(b.y) + bflo(c.y)) * 0.25f;
        o.w = (e.w + bfhi(a.y) + bfhi(b.y) + bfhi(c.y)) * 0.25f;
        out[i] = o;
    }
}

extern "C" void kernel_launch(void* const* d_in, const int* in_sizes, int n_in,
                              void* d_out, int out_size, void* d_ws, size_t ws_size,
                              hipStream_t stream) {
    const float* ue   = (const float*)d_in[0];
    const float* ie   = (const float*)d_in[1];
    const float* vals = (const float*)d_in[2];
    const int*   rows = (const int*)d_in[3];
    const int*   cols = (const int*)d_in[4];
    float* out = (float*)d_out;

    // workspace (~96.3 MB)
    uint2* xa             = (uint2*)d_ws;                          // 19.2 MB
    uint2* xb             = xa + NVEC4;                            // 19.2 MB
    int*   csrc           = (int*)(xb + NVEC4);                    // 19.2 MB
    unsigned short* csrv  = (unsigned short*)(csrc + NNZE);        // 9.6 MB
    int*   stagec         = (int*)(csrv + NNZE);                   // 19.2 MB
    unsigned short* stagev = (unsigned short*)(stagec + NNZE);     // 9.6 MB
    uint2* y3             = (uint2*)stagec;                        // alias (dead after part2)
    int*   rowptr         = (int*)(stagev + NNZE);                 // 150001 ints
    int*   bucketCnt      = rowptr + (NNODES + 1);                 // 512
    int*   bbase          = bucketCnt + NB;                        // 513
    int*   gcur           = bbase + (NB + 1);                      // 512

    const int spmmBlocks = NNODES * 16 / 256;    // 9375

    lg_init<<<2048, 256, 0, stream>>>((const float4*)ue, (const float4*)ie, xa);
    hipMemsetAsync(bucketCnt, 0, NB * sizeof(int), stream);
    lg_bcnt<<<P1_BLOCKS, 512, 0, stream>>>(rows, bucketCnt);
    lg_bscan<<<1, NB, 0, stream>>>(bucketCnt, bbase, gcur);
    lg_part1<<<P1_BLOCKS, 512, 0, stream>>>(rows, cols, vals, gcur, stagec, stagev);
    lg_part2<<<NB, 512, 0, stream>>>(bbase, stagec, stagev, csrc, csrv, rowptr);

    lg_spmm<<<spmmBlocks, 256, 0, stream>>>(rowptr, csrc, csrv, xa, xb);
    lg_spmm<<<spmmBlocks, 256, 0, stream>>>(rowptr, csrc, csrv, xb, xa);
    lg_spmm<<<spmmBlocks, 256, 0, stream>>>(rowptr, csrc, csrv, xa, y3);

    lg_combine<<<2048, 256, 0, stream>>>((const float4*)ue, (const float4*)ie,
                                         xb, xa, y3, (float4*)out);
}

// Round 13
// 372.486 us; speedup vs baseline: 1.0401x; 1.0401x over previous
//
#include <hip/hip_runtime.h>

static constexpr int NUSERS = 100000;
static constexpr int NITEMS = 50000;
static constexpr int NNODES = NUSERS + NITEMS;   // 150000
static constexpr int D      = 64;
static constexpr int NNZE   = 4800000;           // COO entries
static constexpr int NVEC4  = NNODES * D / 4;    // 2.4M 4-col groups
static constexpr int NU4    = NUSERS * D / 4;

static constexpr int NB       = 512;                       // buckets
static constexpr int RPB      = (NNODES + NB - 1) / NB;    // 293 rows/bucket
static constexpr int CHUNK    = 4096;                      // edges per part1 block
static constexpr int P1_BLOCKS = (NNZE + CHUNK - 1) / CHUNK; // 1172

__device__ __forceinline__ unsigned bf16rne(float f) {
    unsigned u = __float_as_uint(f);
    return (u + 0x7FFFu + ((u >> 16) & 1u)) >> 16;   // round-to-nearest-even bf16
}
__device__ __forceinline__ float bflo(unsigned u) { return __uint_as_float(u << 16); }
__device__ __forceinline__ float bfhi(unsigned u) { return __uint_as_float(u & 0xFFFF0000u); }

// ---------- stage: x = ego (packed bf16) ----------
__global__ void lg_init(const float4* __restrict__ ue, const float4* __restrict__ ie,
                        uint2* __restrict__ x) {
    int stride = gridDim.x * blockDim.x;
    for (int i = blockIdx.x * blockDim.x + threadIdx.x; i < NVEC4; i += stride) {
        float4 v = (i < NU4) ? ue[i] : ie[i - NU4];
        x[i] = make_uint2(bf16rne(v.x) | (bf16rne(v.y) << 16),
                          bf16rne(v.z) | (bf16rne(v.w) << 16));
    }
}

// ---------- bucket-level histogram: LDS-privatized, int4 loads ----------
__global__ void __launch_bounds__(512)
lg_bcnt(const int* __restrict__ rows, int* __restrict__ bucketCnt) {
    __shared__ int cnt[NB];
    int t = threadIdx.x;
    cnt[t] = 0;
    __syncthreads();
    int c0 = blockIdx.x * CHUNK;
    int c1 = min(c0 + CHUNK, NNZE);
    #pragma unroll
    for (int pass = 0; pass < 2; ++pass) {
        int e = c0 + (pass * 512 + t) * 4;
        if (e < c1) {
            int4 r4 = *(const int4*)(rows + e);
            atomicAdd(&cnt[r4.x / RPB], 1);
            atomicAdd(&cnt[r4.y / RPB], 1);
            atomicAdd(&cnt[r4.z / RPB], 1);
            atomicAdd(&cnt[r4.w / RPB], 1);
        }
    }
    __syncthreads();
    int n = cnt[t];
    if (n) atomicAdd(&bucketCnt[t], n);
}

// ---------- scan 512 bucket counts -> bbase[513]; seed gcur ----------
__global__ void __launch_bounds__(512)
lg_bscan(const int* __restrict__ bucketCnt, int* __restrict__ bbase,
         int* __restrict__ gcur) {
    __shared__ int s[NB];
    int t = threadIdx.x;
    int v = bucketCnt[t];
    s[t] = v;
    __syncthreads();
    for (int off = 1; off < NB; off <<= 1) {
        int tmp = (t >= off) ? s[t - off] : 0;
        __syncthreads();
        s[t] += tmp;
        __syncthreads();
    }
    int ex = s[t] - v;          // exclusive prefix
    bbase[t] = ex;
    gcur[t] = ex;
    if (t == NB - 1) bbase[NB] = s[t];
}

// ---------- phase 1: bucket partition with LDS-sorted staging ----------
__global__ void __launch_bounds__(512)
lg_part1(const int* __restrict__ rows, const int* __restrict__ cols,
         const float* __restrict__ vals, int* __restrict__ gcur,
         int2* __restrict__ stage) {
    __shared__ int s_cnt[NB];
    __shared__ int s_lcur[NB];
    __shared__ int s_gofs[NB];
    __shared__ int2 s_pay[CHUNK];
    __shared__ unsigned short s_bid[CHUNK];
    int t = threadIdx.x;
    int c0 = blockIdx.x * CHUNK;
    int c1 = min(c0 + CHUNK, NNZE);
    s_cnt[t] = 0;
    __syncthreads();

    int  eb[8], ep[8]; float ev[8];
    bool has0, has1;
    {
        int e = c0 + t * 4;
        has0 = e < c1;
        if (has0) {
            int4 r4 = *(const int4*)(rows + e);
            int4 c4 = *(const int4*)(cols + e);
            float4 v4 = *(const float4*)(vals + e);
            eb[0] = r4.x / RPB; ep[0] = c4.x | ((r4.x - eb[0] * RPB) << 18); ev[0] = v4.x;
            eb[1] = r4.y / RPB; ep[1] = c4.y | ((r4.y - eb[1] * RPB) << 18); ev[1] = v4.y;
            eb[2] = r4.z / RPB; ep[2] = c4.z | ((r4.z - eb[2] * RPB) << 18); ev[2] = v4.z;
            eb[3] = r4.w / RPB; ep[3] = c4.w | ((r4.w - eb[3] * RPB) << 18); ev[3] = v4.w;
            atomicAdd(&s_cnt[eb[0]], 1); atomicAdd(&s_cnt[eb[1]], 1);
            atomicAdd(&s_cnt[eb[2]], 1); atomicAdd(&s_cnt[eb[3]], 1);
        }
        e = c0 + (512 + t) * 4;
        has1 = e < c1;
        if (has1) {
            int4 r4 = *(const int4*)(rows + e);
            int4 c4 = *(const int4*)(cols + e);
            float4 v4 = *(const float4*)(vals + e);
            eb[4] = r4.x / RPB; ep[4] = c4.x | ((r4.x - eb[4] * RPB) << 18); ev[4] = v4.x;
            eb[5] = r4.y / RPB; ep[5] = c4.y | ((r4.y - eb[5] * RPB) << 18); ev[5] = v4.y;
            eb[6] = r4.z / RPB; ep[6] = c4.z | ((r4.z - eb[6] * RPB) << 18); ev[6] = v4.z;
            eb[7] = r4.w / RPB; ep[7] = c4.w | ((r4.w - eb[7] * RPB) << 18); ev[7] = v4.w;
            atomicAdd(&s_cnt[eb[4]], 1); atomicAdd(&s_cnt[eb[5]], 1);
            atomicAdd(&s_cnt[eb[6]], 1); atomicAdd(&s_cnt[eb[7]], 1);
        }
    }
    __syncthreads();

    int myCnt = s_cnt[t];
    for (int off = 1; off < NB; off <<= 1) {
        int tmp = (t >= off) ? s_cnt[t - off] : 0;
        __syncthreads();
        s_cnt[t] += tmp;
        __syncthreads();
    }
    int lstart = s_cnt[t] - myCnt;
    int gbase = myCnt ? atomicAdd(&gcur[t], myCnt) : 0;
    s_lcur[t] = lstart;
    s_gofs[t] = gbase - lstart;
    __syncthreads();

    #pragma unroll
    for (int k = 0; k < 4; ++k) {
        if (has0) {
            int pos = atomicAdd(&s_lcur[eb[k]], 1);
            s_pay[pos] = make_int2(ep[k], __float_as_int(ev[k]));
            s_bid[pos] = (unsigned short)eb[k];
        }
    }
    #pragma unroll
    for (int k = 4; k < 8; ++k) {
        if (has1) {
            int pos = atomicAdd(&s_lcur[eb[k]], 1);
            s_pay[pos] = make_int2(ep[k], __float_as_int(ev[k]));
            s_bid[pos] = (unsigned short)eb[k];
        }
    }
    __syncthreads();

    int n = c1 - c0;
    for (int p = t; p < n; p += 512) {
        int b = s_bid[p];
        stage[s_gofs[b] + p] = s_pay[p];
    }
}

// ---------- phase 2: per-bucket rowptr build + exact CSR placement ----------
__global__ void __launch_bounds__(512)
lg_part2(const int* __restrict__ bbase, const int2* __restrict__ stage,
         int2* __restrict__ csr, int* __restrict__ rowptr) {
    __shared__ int s[NB];
    __shared__ int lcur[RPB];
    int b = blockIdx.x;
    int t = threadIdx.x;
    int r0 = b * RPB;
    int nrows = min(RPB, NNODES - r0);
    int s0 = bbase[b], s1 = bbase[b + 1];

    s[t] = 0;
    __syncthreads();
    for (int p = s0 + t; p < s1; p += 512)
        atomicAdd(&s[(stage[p].x >> 18) & 511], 1);
    __syncthreads();
    int v = s[t];
    for (int off = 1; off < NB; off <<= 1) {
        int tmp = (t >= off) ? s[t - off] : 0;
        __syncthreads();
        s[t] += tmp;
        __syncthreads();
    }
    int pos0 = s0 + s[t] - v;
    if (t < nrows) {
        rowptr[r0 + t] = pos0;
        lcur[t] = pos0;
    }
    if (b == gridDim.x - 1 && t == 0) rowptr[NNODES] = NNZE;
    __syncthreads();
    for (int p = s0 + t; p < s1; p += 512) {
        int2 cv = stage[p];
        int rl = (cv.x >> 18) & 511;
        int pos = atomicAdd(&lcur[rl], 1);
        csr[pos] = make_int2(cv.x & 0x3FFFF, cv.y);
    }
}

// ---------- pull SpMM: 1 row per 16-lane group, unroll-8, cached loads ----------
__global__ void __launch_bounds__(256)
lg_spmm(const int* __restrict__ rowptr, const long long* __restrict__ csr,
        const uint2* __restrict__ x, uint2* __restrict__ y) {
    int lane16 = threadIdx.x & 15;
    int r = (blockIdx.x * blockDim.x + threadIdx.x) >> 4;
    if (r >= NNODES) return;
    int p0 = rowptr[r], p1 = rowptr[r + 1];
    float4 acc = {0.f, 0.f, 0.f, 0.f};
    int p = p0;
    for (; p + 8 <= p1; p += 8) {
        long long cv0 = csr[p],     cv1 = csr[p + 1], cv2 = csr[p + 2], cv3 = csr[p + 3];
        long long cv4 = csr[p + 4], cv5 = csr[p + 5], cv6 = csr[p + 6], cv7 = csr[p + 7];
        uint2 x0 = x[((int)cv0) * 16 + lane16];
        uint2 x1 = x[((int)cv1) * 16 + lane16];
        uint2 x2 = x[((int)cv2) * 16 + lane16];
        uint2 x3 = x[((int)cv3) * 16 + lane16];
        uint2 x4 = x[((int)cv4) * 16 + lane16];
        uint2 x5 = x[((int)cv5) * 16 + lane16];
        uint2 x6 = x[((int)cv6) * 16 + lane16];
        uint2 x7 = x[((int)cv7) * 16 + lane16];
        float v0 = __int_as_float((int)(cv0 >> 32)), v1 = __int_as_float((int)(cv1 >> 32));
        float v2 = __int_as_float((int)(cv2 >> 32)), v3 = __int_as_float((int)(cv3 >> 32));
        float v4 = __int_as_float((int)(cv4 >> 32)), v5 = __int_as_float((int)(cv5 >> 32));
        float v6 = __int_as_float((int)(cv6 >> 32)), v7 = __int_as_float((int)(cv7 >> 32));
        acc.x += v0 * bflo(x0.x) + v1 * bflo(x1.x) + v2 * bflo(x2.x) + v3 * bflo(x3.x)
               + v4 * bflo(x4.x) + v5 * bflo(x5.x) + v6 * bflo(x6.x) + v7 * bflo(x7.x);
        acc.y += v0 * bfhi(x0.x) + v1 * bfhi(x1.x) + v2 * bfhi(x2.x) + v3 * bfhi(x3.x)
               + v4 * bfhi(x4.x) + v5 * bfhi(x5.x) + v6 * bfhi(x6.x) + v7 * bfhi(x7.x);
        acc.z += v0 * bflo(x0.y) + v1 * bflo(x1.y) + v2 * bflo(x2.y) + v3 * bflo(x3.y)
               + v4 * bflo(x4.y) + v5 * bflo(x5.y) + v6 * bflo(x6.y) + v7 * bflo(x7.y);
        acc.w += v0 * bfhi(x0.y) + v1 * bfhi(x1.y) + v2 * bfhi(x2.y) + v3 * bfhi(x3.y)
               + v4 * bfhi(x4.y) + v5 * bfhi(x5.y) + v6 * bfhi(x6.y) + v7 * bfhi(x7.y);
    }
    for (; p + 4 <= p1; p += 4) {
        long long cv0 = csr[p], cv1 = csr[p + 1], cv2 = csr[p + 2], cv3 = csr[p + 3];
        uint2 x0 = x[((int)cv0) * 16 + lane16];
        uint2 x1 = x[((int)cv1) * 16 + lane16];
        uint2 x2 = x[((int)cv2) * 16 + lane16];
        uint2 x3 = x[((int)cv3) * 16 + lane16];
        float v0 = __int_as_float((int)(cv0 >> 32)), v1 = __int_as_float((int)(cv1 >> 32));
        float v2 = __int_as_float((int)(cv2 >> 32)), v3 = __int_as_float((int)(cv3 >> 32));
        acc.x += v0 * bflo(x0.x) + v1 * bflo(x1.x) + v2 * bflo(x2.x) + v3 * bflo(x3.x);
        acc.y += v0 * bfhi(x0.x) + v1 * bfhi(x1.x) + v2 * bfhi(x2.x) + v3 * bfhi(x3.x);
        acc.z += v0 * bflo(x0.y) + v1 * bflo(x1.y) + v2 * bflo(x2.y) + v3 * bflo(x3.y);
        acc.w += v0 * bfhi(x0.y) + v1 * bfhi(x1.y) + v2 * bfhi(x2.y) + v3 * bfhi(x3.y);
    }
    for (; p < p1; ++p) {
        long long cv = csr[p];
        uint2 xv = x[((int)cv) * 16 + lane16];
        float v = __int_as_float((int)(cv >> 32));
        acc.x += v * bflo(xv.x); acc.y += v * bfhi(xv.x);
        acc.z += v * bflo(xv.y); acc.w += v * bfhi(xv.y);
    }
    y[r * 16 + lane16] = make_uint2(bf16rne(acc.x) | (bf16rne(acc.y) << 16),
                                    bf16rne(acc.z) | (bf16rne(acc.w) << 16));
}

// ---------- final combine: out = 0.25 * (ego_fp32 + y1 + y2 + y3) ----------
__global__ void lg_combine(const float4* __restrict__ ue, const float4* __restrict__ ie,
                           const uint2* __restrict__ y1, const uint2* __restrict__ y2,
                           const uint2* __restrict__ y3, float4* __restrict__ out) {
    int stride = gridDim.x * blockDim.x;
    for (int i = blockIdx.x * blockDim.x + threadIdx.x; i < NVEC4; i += stride) {
        float4 e = (i < NU4) ? ue[i] : ie[i - NU4];
        uint2 a = y1[i], b = y2[i], c = y3[i];
        float4 o;
        o.x = (e.x + bflo(a.x) + bflo(b.x) + bflo(c.x)) * 0.25f;
        o.y = (e.y + bfhi(a.x) + bfhi(b.x) + bfhi(c.x)) * 0.25f;
        o.z = (e.z + bflo(a.y) + bflo(b.y) + bflo(c.y)) * 0.25f;
        o.w = (e.w + bfhi(a.y) + bfhi(b.y) + bfhi(c.y)) * 0.25f;
        out[i] = o;
    }
}

extern "C" void kernel_launch(void* const* d_in, const int* in_sizes, int n_in,
                              void* d_out, int out_size, void* d_ws, size_t ws_size,
                              hipStream_t stream) {
    const float* ue   = (const float*)d_in[0];
    const float* ie   = (const float*)d_in[1];
    const float* vals = (const float*)d_in[2];
    const int*   rows = (const int*)d_in[3];
    const int*   cols = (const int*)d_in[4];
    float* out = (float*)d_out;

    // workspace (~115.8 MB)
    uint2* xa     = (uint2*)d_ws;                // 19.2 MB (bf16 ego -> y2)
    uint2* xb     = xa + NVEC4;                  // 19.2 MB (y1)
    int2*  csr    = (int2*)(xb + NVEC4);         // 38.4 MB
    int2*  stage  = csr + NNZE;                  // 38.4 MB (dead after part2)
    uint2* y3     = (uint2*)stage;               // 19.2 MB alias onto stage
    int*   rowptr = (int*)(stage + NNZE);        // 150001 ints
    int*   bucketCnt = rowptr + (NNODES + 1);    // 512
    int*   bbase  = bucketCnt + NB;              // 513
    int*   gcur   = bbase + (NB + 1);            // 512

    const int spmmBlocks = NNODES * 16 / 256;    // 9375

    lg_init<<<2048, 256, 0, stream>>>((const float4*)ue, (const float4*)ie, xa);
    hipMemsetAsync(bucketCnt, 0, NB * sizeof(int), stream);
    lg_bcnt<<<P1_BLOCKS, 512, 0, stream>>>(rows, bucketCnt);
    lg_bscan<<<1, NB, 0, stream>>>(bucketCnt, bbase, gcur);
    lg_part1<<<P1_BLOCKS, 512, 0, stream>>>(rows, cols, vals, gcur, stage);
    lg_part2<<<NB, 512, 0, stream>>>(bbase, stage, csr, rowptr);

    lg_spmm<<<spmmBlocks, 256, 0, stream>>>(rowptr, (const long long*)csr, xa, xb);   // y1 = A*ego
    lg_spmm<<<spmmBlocks, 256, 0, stream>>>(rowptr, (const long long*)csr, xb, xa);   // y2 = A*y1
    lg_spmm<<<spmmBlocks, 256, 0, stream>>>(rowptr, (const long long*)csr, xa, y3);   // y3 = A*y2

    lg_combine<<<2048, 256, 0, stream>>>((const float4*)ue, (const float4*)ie,
                                         xb, xa, y3, (float4*)out);
}

// Round 14
// 361.705 us; speedup vs baseline: 1.0711x; 1.0298x over previous
//
#include <hip/hip_runtime.h>

static constexpr int NUSERS = 100000;
static constexpr int NITEMS = 50000;
static constexpr int NNODES = NUSERS + NITEMS;   // 150000
static constexpr int D      = 64;
static constexpr int NNZE   = 4800000;           // COO entries
static constexpr int NVEC4  = NNODES * D / 4;    // 2.4M 4-col groups
static constexpr int NU4    = NUSERS * D / 4;

static constexpr int NB       = 512;                       // buckets
static constexpr int RPB      = (NNODES + NB - 1) / NB;    // 293 rows/bucket
static constexpr int CHUNK    = 4096;                      // edges per part1 block
static constexpr int P1_BLOCKS = (NNZE + CHUNK - 1) / CHUNK; // 1172

__device__ __forceinline__ unsigned bf16rne(float f) {
    unsigned u = __float_as_uint(f);
    return (u + 0x7FFFu + ((u >> 16) & 1u)) >> 16;   // round-to-nearest-even bf16
}
__device__ __forceinline__ float bflo(unsigned u) { return __uint_as_float(u << 16); }
__device__ __forceinline__ float bfhi(unsigned u) { return __uint_as_float(u & 0xFFFF0000u); }

// ---------- stage: x = ego (packed bf16) ----------
__global__ void lg_init(const float4* __restrict__ ue, const float4* __restrict__ ie,
                        uint2* __restrict__ x) {
    int stride = gridDim.x * blockDim.x;
    for (int i = blockIdx.x * blockDim.x + threadIdx.x; i < NVEC4; i += stride) {
        float4 v = (i < NU4) ? ue[i] : ie[i - NU4];
        x[i] = make_uint2(bf16rne(v.x) | (bf16rne(v.y) << 16),
                          bf16rne(v.z) | (bf16rne(v.w) << 16));
    }
}

// ---------- bucket-level histogram: LDS-privatized, int4 loads ----------
__global__ void __launch_bounds__(512)
lg_bcnt(const int* __restrict__ rows, int* __restrict__ bucketCnt) {
    __shared__ int cnt[NB];
    int t = threadIdx.x;
    cnt[t] = 0;
    __syncthreads();
    int c0 = blockIdx.x * CHUNK;
    int c1 = min(c0 + CHUNK, NNZE);
    #pragma unroll
    for (int pass = 0; pass < 2; ++pass) {
        int e = c0 + (pass * 512 + t) * 4;
        if (e < c1) {
            int4 r4 = *(const int4*)(rows + e);
            atomicAdd(&cnt[r4.x / RPB], 1);
            atomicAdd(&cnt[r4.y / RPB], 1);
            atomicAdd(&cnt[r4.z / RPB], 1);
            atomicAdd(&cnt[r4.w / RPB], 1);
        }
    }
    __syncthreads();
    int n = cnt[t];
    if (n) atomicAdd(&bucketCnt[t], n);
}

// ---------- scan 512 bucket counts -> bbase[513]; seed gcur ----------
__global__ void __launch_bounds__(512)
lg_bscan(const int* __restrict__ bucketCnt, int* __restrict__ bbase,
         int* __restrict__ gcur) {
    __shared__ int s[NB];
    int t = threadIdx.x;
    int v = bucketCnt[t];
    s[t] = v;
    __syncthreads();
    for (int off = 1; off < NB; off <<= 1) {
        int tmp = (t >= off) ? s[t - off] : 0;
        __syncthreads();
        s[t] += tmp;
        __syncthreads();
    }
    int ex = s[t] - v;          // exclusive prefix
    bbase[t] = ex;
    gcur[t] = ex;
    if (t == NB - 1) bbase[NB] = s[t];
}

// ---------- phase 1: bucket partition with LDS-sorted staging ----------
__global__ void __launch_bounds__(512)
lg_part1(const int* __restrict__ rows, const int* __restrict__ cols,
         const float* __restrict__ vals, int* __restrict__ gcur,
         int2* __restrict__ stage) {
    __shared__ int s_cnt[NB];
    __shared__ int s_lcur[NB];
    __shared__ int s_gofs[NB];
    __shared__ int2 s_pay[CHUNK];
    __shared__ unsigned short s_bid[CHUNK];
    int t = threadIdx.x;
    int c0 = blockIdx.x * CHUNK;
    int c1 = min(c0 + CHUNK, NNZE);
    s_cnt[t] = 0;
    __syncthreads();

    int  eb[8], ep[8]; float ev[8];
    bool has0, has1;
    {
        int e = c0 + t * 4;
        has0 = e < c1;
        if (has0) {
            int4 r4 = *(const int4*)(rows + e);
            int4 c4 = *(const int4*)(cols + e);
            float4 v4 = *(const float4*)(vals + e);
            eb[0] = r4.x / RPB; ep[0] = c4.x | ((r4.x - eb[0] * RPB) << 18); ev[0] = v4.x;
            eb[1] = r4.y / RPB; ep[1] = c4.y | ((r4.y - eb[1] * RPB) << 18); ev[1] = v4.y;
            eb[2] = r4.z / RPB; ep[2] = c4.z | ((r4.z - eb[2] * RPB) << 18); ev[2] = v4.z;
            eb[3] = r4.w / RPB; ep[3] = c4.w | ((r4.w - eb[3] * RPB) << 18); ev[3] = v4.w;
            atomicAdd(&s_cnt[eb[0]], 1); atomicAdd(&s_cnt[eb[1]], 1);
            atomicAdd(&s_cnt[eb[2]], 1); atomicAdd(&s_cnt[eb[3]], 1);
        }
        e = c0 + (512 + t) * 4;
        has1 = e < c1;
        if (has1) {
            int4 r4 = *(const int4*)(rows + e);
            int4 c4 = *(const int4*)(cols + e);
            float4 v4 = *(const float4*)(vals + e);
            eb[4] = r4.x / RPB; ep[4] = c4.x | ((r4.x - eb[4] * RPB) << 18); ev[4] = v4.x;
            eb[5] = r4.y / RPB; ep[5] = c4.y | ((r4.y - eb[5] * RPB) << 18); ev[5] = v4.y;
            eb[6] = r4.z / RPB; ep[6] = c4.z | ((r4.z - eb[6] * RPB) << 18); ev[6] = v4.z;
            eb[7] = r4.w / RPB; ep[7] = c4.w | ((r4.w - eb[7] * RPB) << 18); ev[7] = v4.w;
            atomicAdd(&s_cnt[eb[4]], 1); atomicAdd(&s_cnt[eb[5]], 1);
            atomicAdd(&s_cnt[eb[6]], 1); atomicAdd(&s_cnt[eb[7]], 1);
        }
    }
    __syncthreads();

    int myCnt = s_cnt[t];
    for (int off = 1; off < NB; off <<= 1) {
        int tmp = (t >= off) ? s_cnt[t - off] : 0;
        __syncthreads();
        s_cnt[t] += tmp;
        __syncthreads();
    }
    int lstart = s_cnt[t] - myCnt;
    int gbase = myCnt ? atomicAdd(&gcur[t], myCnt) : 0;
    s_lcur[t] = lstart;
    s_gofs[t] = gbase - lstart;
    __syncthreads();

    #pragma unroll
    for (int k = 0; k < 4; ++k) {
        if (has0) {
            int pos = atomicAdd(&s_lcur[eb[k]], 1);
            s_pay[pos] = make_int2(ep[k], __float_as_int(ev[k]));
            s_bid[pos] = (unsigned short)eb[k];
        }
    }
    #pragma unroll
    for (int k = 4; k < 8; ++k) {
        if (has1) {
            int pos = atomicAdd(&s_lcur[eb[k]], 1);
            s_pay[pos] = make_int2(ep[k], __float_as_int(ev[k]));
            s_bid[pos] = (unsigned short)eb[k];
        }
    }
    __syncthreads();

    int n = c1 - c0;
    for (int p = t; p < n; p += 512) {
        int b = s_bid[p];
        stage[s_gofs[b] + p] = s_pay[p];
    }
}

// ---------- phase 2: per-bucket rowptr build + exact CSR placement ----------
__global__ void __launch_bounds__(512)
lg_part2(const int* __restrict__ bbase, const int2* __restrict__ stage,
         int2* __restrict__ csr, int* __restrict__ rowptr) {
    __shared__ int s[NB];
    __shared__ int lcur[RPB];
    int b = blockIdx.x;
    int t = threadIdx.x;
    int r0 = b * RPB;
    int nrows = min(RPB, NNODES - r0);
    int s0 = bbase[b], s1 = bbase[b + 1];

    s[t] = 0;
    __syncthreads();
    for (int p = s0 + t; p < s1; p += 512)
        atomicAdd(&s[(stage[p].x >> 18) & 511], 1);
    __syncthreads();
    int v = s[t];
    for (int off = 1; off < NB; off <<= 1) {
        int tmp = (t >= off) ? s[t - off] : 0;
        __syncthreads();
        s[t] += tmp;
        __syncthreads();
    }
    int pos0 = s0 + s[t] - v;
    if (t < nrows) {
        rowptr[r0 + t] = pos0;
        lcur[t] = pos0;
    }
    if (b == gridDim.x - 1 && t == 0) rowptr[NNODES] = NNZE;
    __syncthreads();
    for (int p = s0 + t; p < s1; p += 512) {
        int2 cv = stage[p];
        int rl = (cv.x >> 18) & 511;
        int pos = atomicAdd(&lcur[rl], 1);
        csr[pos] = make_int2(cv.x & 0x3FFFF, cv.y);
    }
}

// ---------- pull SpMM: 1 row per 16-lane group, unroll-8, cached loads ----------
// MODE 0: y = bf16(A*x)
// MODE 1: out = 0.25 * (ego_fp32 + y1 + x_row + acc)   (fused final combine;
//         x = y2, acc = y3 kept in fp32 — no y write)
template<int MODE>
__global__ void __launch_bounds__(256)
lg_spmm(const int* __restrict__ rowptr, const long long* __restrict__ csr,
        const uint2* __restrict__ x, uint2* __restrict__ y,
        const float4* __restrict__ ue, const float4* __restrict__ ie,
        const uint2* __restrict__ y1, float4* __restrict__ out) {
    int lane16 = threadIdx.x & 15;
    int r = (blockIdx.x * blockDim.x + threadIdx.x) >> 4;
    if (r >= NNODES) return;
    int p0 = rowptr[r], p1 = rowptr[r + 1];
    float4 acc = {0.f, 0.f, 0.f, 0.f};
    int p = p0;
    for (; p + 8 <= p1; p += 8) {
        long long cv0 = csr[p],     cv1 = csr[p + 1], cv2 = csr[p + 2], cv3 = csr[p + 3];
        long long cv4 = csr[p + 4], cv5 = csr[p + 5], cv6 = csr[p + 6], cv7 = csr[p + 7];
        uint2 x0 = x[((int)cv0) * 16 + lane16];
        uint2 x1 = x[((int)cv1) * 16 + lane16];
        uint2 x2 = x[((int)cv2) * 16 + lane16];
        uint2 x3 = x[((int)cv3) * 16 + lane16];
        uint2 x4 = x[((int)cv4) * 16 + lane16];
        uint2 x5 = x[((int)cv5) * 16 + lane16];
        uint2 x6 = x[((int)cv6) * 16 + lane16];
        uint2 x7 = x[((int)cv7) * 16 + lane16];
        float v0 = __int_as_float((int)(cv0 >> 32)), v1 = __int_as_float((int)(cv1 >> 32));
        float v2 = __int_as_float((int)(cv2 >> 32)), v3 = __int_as_float((int)(cv3 >> 32));
        float v4 = __int_as_float((int)(cv4 >> 32)), v5 = __int_as_float((int)(cv5 >> 32));
        float v6 = __int_as_float((int)(cv6 >> 32)), v7 = __int_as_float((int)(cv7 >> 32));
        acc.x += v0 * bflo(x0.x) + v1 * bflo(x1.x) + v2 * bflo(x2.x) + v3 * bflo(x3.x)
               + v4 * bflo(x4.x) + v5 * bflo(x5.x) + v6 * bflo(x6.x) + v7 * bflo(x7.x);
        acc.y += v0 * bfhi(x0.x) + v1 * bfhi(x1.x) + v2 * bfhi(x2.x) + v3 * bfhi(x3.x)
               + v4 * bfhi(x4.x) + v5 * bfhi(x5.x) + v6 * bfhi(x6.x) + v7 * bfhi(x7.x);
        acc.z += v0 * bflo(x0.y) + v1 * bflo(x1.y) + v2 * bflo(x2.y) + v3 * bflo(x3.y)
               + v4 * bflo(x4.y) + v5 * bflo(x5.y) + v6 * bflo(x6.y) + v7 * bflo(x7.y);
        acc.w += v0 * bfhi(x0.y) + v1 * bfhi(x1.y) + v2 * bfhi(x2.y) + v3 * bfhi(x3.y)
               + v4 * bfhi(x4.y) + v5 * bfhi(x5.y) + v6 * bfhi(x6.y) + v7 * bfhi(x7.y);
    }
    for (; p + 4 <= p1; p += 4) {
        long long cv0 = csr[p], cv1 = csr[p + 1], cv2 = csr[p + 2], cv3 = csr[p + 3];
        uint2 x0 = x[((int)cv0) * 16 + lane16];
        uint2 x1 = x[((int)cv1) * 16 + lane16];
        uint2 x2 = x[((int)cv2) * 16 + lane16];
        uint2 x3 = x[((int)cv3) * 16 + lane16];
        float v0 = __int_as_float((int)(cv0 >> 32)), v1 = __int_as_float((int)(cv1 >> 32));
        float v2 = __int_as_float((int)(cv2 >> 32)), v3 = __int_as_float((int)(cv3 >> 32));
        acc.x += v0 * bflo(x0.x) + v1 * bflo(x1.x) + v2 * bflo(x2.x) + v3 * bflo(x3.x);
        acc.y += v0 * bfhi(x0.x) + v1 * bfhi(x1.x) + v2 * bfhi(x2.x) + v3 * bfhi(x3.x);
        acc.z += v0 * bflo(x0.y) + v1 * bflo(x1.y) + v2 * bflo(x2.y) + v3 * bflo(x3.y);
        acc.w += v0 * bfhi(x0.y) + v1 * bfhi(x1.y) + v2 * bfhi(x2.y) + v3 * bfhi(x3.y);
    }
    for (; p < p1; ++p) {
        long long cv = csr[p];
        uint2 xv = x[((int)cv) * 16 + lane16];
        float v = __int_as_float((int)(cv >> 32));
        acc.x += v * bflo(xv.x); acc.y += v * bfhi(xv.x);
        acc.z += v * bflo(xv.y); acc.w += v * bfhi(xv.y);
    }
    int idx = r * 16 + lane16;
    if (MODE == 0) {
        y[idx] = make_uint2(bf16rne(acc.x) | (bf16rne(acc.y) << 16),
                            bf16rne(acc.z) | (bf16rne(acc.w) << 16));
    } else {
        float4 ego = (r < NUSERS) ? ue[idx] : ie[idx - NUSERS * 16];
        uint2 a = y1[idx];   // layer-1 output (bf16)
        uint2 b = x[idx];    // layer-2 output = this pass's own-row x (bf16, L2-hot)
        float4 o;
        o.x = (ego.x + bflo(a.x) + bflo(b.x) + acc.x) * 0.25f;
        o.y = (ego.y + bfhi(a.x) + bfhi(b.x) + acc.y) * 0.25f;
        o.z = (ego.z + bflo(a.y) + bflo(b.y) + acc.z) * 0.25f;
        o.w = (ego.w + bfhi(a.y) + bfhi(b.y) + acc.w) * 0.25f;
        out[idx] = o;
    }
}

extern "C" void kernel_launch(void* const* d_in, const int* in_sizes, int n_in,
                              void* d_out, int out_size, void* d_ws, size_t ws_size,
                              hipStream_t stream) {
    const float* ue   = (const float*)d_in[0];
    const float* ie   = (const float*)d_in[1];
    const float* vals = (const float*)d_in[2];
    const int*   rows = (const int*)d_in[3];
    const int*   cols = (const int*)d_in[4];
    float* out = (float*)d_out;

    // workspace (~96.6 MB)
    uint2* xa     = (uint2*)d_ws;                // 19.2 MB (bf16 ego -> y2)
    uint2* xb     = xa + NVEC4;                  // 19.2 MB (y1)
    int2*  csr    = (int2*)(xb + NVEC4);         // 38.4 MB
    int2*  stage  = csr + NNZE;                  // 38.4 MB (dead after part2)
    int*   rowptr = (int*)(stage + NNZE);        // 150001 ints
    int*   bucketCnt = rowptr + (NNODES + 1);    // 512
    int*   bbase  = bucketCnt + NB;              // 513
    int*   gcur   = bbase + (NB + 1);            // 512

    const int spmmBlocks = NNODES * 16 / 256;    // 9375

    lg_init<<<2048, 256, 0, stream>>>((const float4*)ue, (const float4*)ie, xa);
    hipMemsetAsync(bucketCnt, 0, NB * sizeof(int), stream);
    lg_bcnt<<<P1_BLOCKS, 512, 0, stream>>>(rows, bucketCnt);
    lg_bscan<<<1, NB, 0, stream>>>(bucketCnt, bbase, gcur);
    lg_part1<<<P1_BLOCKS, 512, 0, stream>>>(rows, cols, vals, gcur, stage);
    lg_part2<<<NB, 512, 0, stream>>>(bbase, stage, csr, rowptr);

    // y1 = A*ego ; y2 = A*y1 ; out = 0.25*(ego + y1 + y2 + A*y2)  (fused)
    lg_spmm<0><<<spmmBlocks, 256, 0, stream>>>(rowptr, (const long long*)csr, xa, xb,
                                               nullptr, nullptr, nullptr, nullptr);
    lg_spmm<0><<<spmmBlocks, 256, 0, stream>>>(rowptr, (const long long*)csr, xb, xa,
                                               nullptr, nullptr, nullptr, nullptr);
    lg_spmm<1><<<spmmBlocks, 256, 0, stream>>>(rowptr, (const long long*)csr, xa, nullptr,
                                               (const float4*)ue, (const float4*)ie,
                                               xb, (float4*)out);
}